// Round 8
// baseline (3989.123 us; speedup 1.0000x reference)
//
#include <hip/hip_runtime.h>
#include <math.h>

// ---------------- problem dims ----------------
#define BB   512   // batch
#define TT   64    // timesteps
#define AD   6     // action dim
#define HD   256   // obs feature dim
#define RD   256   // recurrent dim
#define LD   1024  // latent dim
#define GD   768   // 3*RD (gate order r,z,n)

// ---------------- workspace layout (float offsets) ----------------
#define OFF_WIHT    0u          // W_ih^T          256x768
#define OFF_WHHT    196608u     // W_hh^T          256x768
#define OFF_WPOSTT  393216u     // W_post^T        512x1024
#define OFF_WCT     917504u     // (W_ih@W_in)^T   1030x768 (row = input col)
#define OFF_BC      1708544u    // b_c = W_ih@b_in + b_ih   768
#define OFF_OBSPROJ 1709312u    // obs_proj        32768x1024
#define WS_FLOATS_FULL (OFF_OBSPROJ + (size_t)32768 * 1024)

__device__ __forceinline__ void fma4(float4& a, const float4 w, const float s) {
  a.x = fmaf(w.x, s, a.x); a.y = fmaf(w.y, s, a.y);
  a.z = fmaf(w.z, s, a.z); a.w = fmaf(w.w, s, a.w);
}
__device__ __forceinline__ void fma2(float2& a, const float2 w, const float s) {
  a.x = fmaf(w.x, s, a.x); a.y = fmaf(w.y, s, a.y);
}
// non-temporal (evict-first) helpers — numerics-neutral (ext-vector bridge, R3 fix)
typedef float fvec4 __attribute__((ext_vector_type(4)));
__device__ __forceinline__ float4 ntload4(const float* p) {
  const fvec4 v = __builtin_nontemporal_load((const fvec4*)p);
  return make_float4(v.x, v.y, v.z, v.w);
}
__device__ __forceinline__ void ntstore4(float* p, const float4 v) {
  fvec4 w; w.x = v.x; w.y = v.y; w.z = v.z; w.w = v.w;
  __builtin_nontemporal_store(w, (fvec4*)p);
}

// ---------------- tiled transpose: dst[c*R+r] = src[r*C+c] ----------------
__global__ __launch_bounds__(256) void transpose_k(const float* __restrict__ src,
                                                   float* __restrict__ dst,
                                                   int R, int C) {
  __shared__ float t_s[32][33];
  const int tx = threadIdx.x, ty = threadIdx.y;
  const int c0 = blockIdx.x * 32, r0 = blockIdx.y * 32;
#pragma unroll
  for (int k = 0; k < 4; ++k)
    t_s[ty + k*8][tx] = src[(size_t)(r0 + ty + k*8) * C + c0 + tx];
  __syncthreads();
#pragma unroll
  for (int k = 0; k < 4; ++k)
    dst[(size_t)(c0 + ty + k*8) * R + r0 + tx] = t_s[tx][ty + k*8];
}

// ---------------- W_c = W_ih @ W_in fused-input matrix (transposed) ----------------
__global__ __launch_bounds__(256) void wc_kernel(const float* __restrict__ W_in,
                                                 const float* __restrict__ b_in,
                                                 const float* __restrict__ WihT,
                                                 const float* __restrict__ b_ih,
                                                 float* __restrict__ WcT,
                                                 float* __restrict__ bc) {
  __shared__ float v_s[256];
  const int tid = threadIdx.x;
  const int col = blockIdx.x;           // 0..1030
  v_s[tid] = (col < 1030) ? W_in[(size_t)tid * 1030 + col] : b_in[tid];
  __syncthreads();
  float a0 = 0.f, a1 = 0.f, a2 = 0.f;
#pragma unroll 4
  for (int h = 0; h < 256; ++h) {
    const float v = v_s[h];
    const float* row = &WihT[(size_t)h * GD];
    a0 = fmaf(row[tid      ], v, a0);
    a1 = fmaf(row[tid + 256], v, a1);
    a2 = fmaf(row[tid + 512], v, a2);
  }
  if (col < 1030) {
    WcT[(size_t)col * GD + tid      ] = a0;
    WcT[(size_t)col * GD + tid + 256] = a1;
    WcT[(size_t)col * GD + tid + 512] = a2;
  } else {
    bc[tid      ] = b_ih[tid      ] + a0;
    bc[tid + 256] = b_ih[tid + 256] + a1;
    bc[tid + 512] = b_ih[tid + 512] + a2;
  }
}

// ---------------- obs_proj[m][l] = b_post[l] + sum_h obs[m][h]*W_post[l][256+h] ----
__global__ __launch_bounds__(256) void obsproj_gemm(const float* __restrict__ obs,
                                                    const float* __restrict__ Wpost,
                                                    const float* __restrict__ bpost,
                                                    float* __restrict__ outp) {
  __shared__ __align__(16) float As[32][132];
  __shared__ __align__(16) float Bs[32][132];
  const int tid = threadIdx.x;
  const int tx = tid & 15, ty = tid >> 4;
  const int m0 = blockIdx.y * 128, n0 = blockIdx.x * 128;
  float acc[8][8];
#pragma unroll
  for (int i = 0; i < 8; ++i)
#pragma unroll
    for (int j = 0; j < 8; ++j) acc[i][j] = 0.f;

  for (int k0 = 0; k0 < 256; k0 += 32) {
#pragma unroll
    for (int it = 0; it < 4; ++it) {
      const int idx = tid + it * 256;        // 0..1023
      const int mi = idx >> 3, k4 = (idx & 7) * 4;
      float4 va = *(const float4*)&obs[(size_t)(m0 + mi) * 256 + k0 + k4];
      As[k4+0][mi] = va.x; As[k4+1][mi] = va.y; As[k4+2][mi] = va.z; As[k4+3][mi] = va.w;
      float4 vb = *(const float4*)&Wpost[(size_t)(n0 + mi) * 512 + 256 + k0 + k4];
      Bs[k4+0][mi] = vb.x; Bs[k4+1][mi] = vb.y; Bs[k4+2][mi] = vb.z; Bs[k4+3][mi] = vb.w;
    }
    __syncthreads();
#pragma unroll 8
    for (int k = 0; k < 32; ++k) {
      float4 a0 = *(const float4*)&As[k][ty*4];
      float4 a1 = *(const float4*)&As[k][64 + ty*4];
      float4 b0 = *(const float4*)&Bs[k][tx*4];
      float4 b1 = *(const float4*)&Bs[k][64 + tx*4];
      float av[8] = {a0.x,a0.y,a0.z,a0.w,a1.x,a1.y,a1.z,a1.w};
      float bv[8] = {b0.x,b0.y,b0.z,b0.w,b1.x,b1.y,b1.z,b1.w};
#pragma unroll
      for (int i = 0; i < 8; ++i)
#pragma unroll
        for (int j = 0; j < 8; ++j) acc[i][j] = fmaf(av[i], bv[j], acc[i][j]);
    }
    __syncthreads();
  }
  float4 bp0 = *(const float4*)&bpost[n0 + tx*4];
  float4 bp1 = *(const float4*)&bpost[n0 + 64 + tx*4];
#pragma unroll
  for (int i = 0; i < 8; ++i) {
    const int mi = (i < 4) ? (ty*4 + i) : (64 + ty*4 + (i - 4));
    float4 c0, c1;
    c0.x = acc[i][0] + bp0.x; c0.y = acc[i][1] + bp0.y;
    c0.z = acc[i][2] + bp0.z; c0.w = acc[i][3] + bp0.w;
    c1.x = acc[i][4] + bp1.x; c1.y = acc[i][5] + bp1.y;
    c1.z = acc[i][6] + bp1.z; c1.w = acc[i][7] + bp1.w;
    ntstore4(&outp[(size_t)(m0 + mi) * 1024 + n0 + tx*4], c0);
    ntstore4(&outp[(size_t)(m0 + mi) * 1024 + n0 + 64 + tx*4], c1);
  }
}

// ================= pipelined load/FMA groups (bit-exact FMA order, NB=1) ============
#define GH_LOAD(W, g) {                                                   \
    const int cg_ = (g) * 4;                                              \
    W[0] = wp[(size_t)(cg_ + 0) * 192];                                   \
    W[1] = wp[(size_t)(cg_ + 1) * 192];                                   \
    W[2] = wp[(size_t)(cg_ + 2) * 192];                                   \
    W[3] = wp[(size_t)(cg_ + 3) * 192];                                   \
  }
#define GH_LOADL(W) {                                                     \
    W[0] = ((const float4*)wpin_gh[half][0])[rg];                         \
    W[1] = ((const float4*)wpin_gh[half][1])[rg];                         \
    W[2] = ((const float4*)wpin_gh[half][2])[rg];                         \
    W[3] = ((const float4*)wpin_gh[half][3])[rg];                         \
  }
#define GH_FMA(W, g) {                                                    \
    const int cg_ = (g) * 4;                                              \
    const float4 d0 = *(const float4*)&deter_s[cbase + cg_];              \
    fma4(acc0, W[0], d0.x); fma4(acc0, W[1], d0.y); fma4(acc0, W[2], d0.z); fma4(acc0, W[3], d0.w); \
  }
// WcT gather: cached loads (64 batches/XCD share gather columns in L2)
#define GI_LOAD(W, g) {                                                   \
    W[0] = Wc4[(size_t)scol_s[(g)*4 + 0] * 192 + rg];                     \
    W[1] = Wc4[(size_t)scol_s[(g)*4 + 1] * 192 + rg];                     \
    W[2] = Wc4[(size_t)scol_s[(g)*4 + 2] * 192 + rg];                     \
    W[3] = Wc4[(size_t)scol_s[(g)*4 + 3] * 192 + rg];                     \
  }
#define GI_ADD(W) {                                                       \
    acc.x += W[0].x; acc.y += W[0].y; acc.z += W[0].z; acc.w += W[0].w;   \
    acc.x += W[1].x; acc.y += W[1].y; acc.z += W[1].z; acc.w += W[1].w;   \
    acc.x += W[2].x; acc.y += W[2].y; acc.z += W[2].z; acc.w += W[2].w;   \
    acc.x += W[3].x; acc.y += W[3].y; acc.z += W[3].z; acc.w += W[3].w;   \
  }
#define PP_LOAD(W, g) {                                                   \
    const int cg_ = (g) * 4;                                              \
    W[0] = pp2w[(size_t)(cg_ + 0) * 512];                                 \
    W[1] = pp2w[(size_t)(cg_ + 1) * 512];                                 \
    W[2] = pp2w[(size_t)(cg_ + 2) * 512];                                 \
    W[3] = pp2w[(size_t)(cg_ + 3) * 512];                                 \
  }
#define PP_FMA(W, g) {                                                    \
    const int cg_ = (g) * 4;                                              \
    const float4 d0 = *(const float4*)&deter_s[cbase + cg_];              \
    fma2(acc0, W[0], d0.x); fma2(acc0, W[1], d0.y); fma2(acc0, W[2], d0.z); fma2(acc0, W[3], d0.w); \
  }

// ---------------- recurrent scan: 512 blocks x 1024 threads, 1 batch/block ----------
// 2 independent blocks per CU (32 waves): one block's compute covers the other's
// barrier drains and load latency. LDS 43KB/block; VGPR forced <=64 via
// __launch_bounds__(1024, 8). Per-output FMA order identical to prior versions.
__global__ __launch_bounds__(1024, 8) void rssm_scan(
    const float* __restrict__ obs, const float* __restrict__ action,
    const int* __restrict__ first, const float* __restrict__ gumbel,
    const float* __restrict__ WhhT, const float* __restrict__ WpostT,
    const float* __restrict__ WcT, const float* __restrict__ bc,
    const float* __restrict__ bhh, const float* __restrict__ bpost,
    const float* __restrict__ obsproj,   // null => fold obs into posterior loop
    float* __restrict__ out_deter, float* __restrict__ out_stoch,
    float* __restrict__ out_logits) {
  union SharedU {
    struct { float gi[GD]; float ghp[2][GD]; } g;   // 3KB + 6KB
    float pp[2][LD];                                // 8KB
  };
  __shared__ SharedU u;
  __shared__ __align__(16) float deter_s[RD];      // 1KB
  __shared__ __align__(16) float obs_s[HD];        // 1KB (fallback only)
  __shared__ float act_all[TT][AD];                // 1.5KB
  __shared__ int   first_all[TT];                  // 0.25KB
  __shared__ float bc_s[GD];                       // 3KB
  __shared__ float bhh_s[GD];                      // 3KB
  __shared__ int   scol_s[32];
  // pinned WhhT group 0 (loaded once; same values, consumed in same order)
  __shared__ __align__(16) float wpin_gh[2][4][768];      // 24KB

  const int tid = threadIdx.x;
  const int b0 = blockIdx.x;                 // one batch per block
  const bool use_op = (obsproj != nullptr);
  const float4* Wc4 = (const float4*)WcT;    // [col][192 float4]
  const float4* Wh4 = (const float4*)WhhT;   // [c][192 float4]
  const float2* Wp2 = (const float2*)WpostT; // [c][512 float2]

  // ---- one-time preload ----
  if (tid < RD) deter_s[tid] = 0.f;
  if (tid < TT * AD) act_all[tid / AD][tid % AD] = action[(size_t)b0 * TT * AD + tid];
  if (tid < TT) first_all[tid] = first[b0 * TT + tid];
  if (tid < GD) { bc_s[tid] = bc[tid]; bhh_s[tid] = bhh[tid]; }
  for (int i = tid; i < 1536; i += 1024) {
    const int hf = i / 768, r = i % 768, c = r / 192, rg = r % 192;
    ((float4*)wpin_gh[hf][c])[rg] = Wh4[(size_t)(hf * 128 + c) * 192 + rg];
  }
  __syncthreads();

  const int o4me = tid & 255;   // P4 identity mapping (tid < 256)

  for (int t = 0; t < TT; ++t) {
    // ---- register prefetch for P4 (flies under P1..P3), threads 0..255 ----
    float4 op4, g4;
    if (tid < 256) {
      if (use_op)
        op4 = ntload4(&obsproj[(((size_t)b0 * TT + t) * LD) + o4me * 4]);
      else
        op4 = *(const float4*)&bpost[o4me * 4];
      g4 = ntload4(&gumbel[(((size_t)t * BB + b0) * LD) + o4me * 4]);
    }

    // ================= P1 =================
    if (tid < 384) {
      // gh: half of K per thread-set; group 0 from LDS, groups 1..31 pipelined
      const int half = (tid < 192) ? 0 : 1;
      const int rg = tid - half * 192;
      const int cbase = half * 128;
      float4 acc0;
      if (half == 0) acc0 = *(const float4*)&bhh_s[rg * 4];
      else           acc0 = make_float4(0.f, 0.f, 0.f, 0.f);
      const float4* wp = &Wh4[(size_t)cbase * 192 + rg];
      float4 wA[4], wB[4], wC[4];
      GH_LOAD(wA, 1); GH_LOAD(wB, 2);
      GH_LOADL(wC); GH_FMA(wC, 0);
#pragma unroll 1
      for (int gg = 0; gg < 9; ++gg) {
        const int g = 1 + gg * 3;
        GH_LOAD(wC, g + 2); GH_FMA(wA, g);
        GH_LOAD(wA, g + 3); GH_FMA(wB, g + 1);
        GH_LOAD(wB, g + 4); GH_FMA(wC, g + 2);
      }
      // after loop: wA=g28, wB=g29; remaining FMAs 28..31
      GH_LOAD(wC, 30); GH_FMA(wA, 28);
      GH_LOAD(wA, 31); GH_FMA(wB, 29);
      GH_FMA(wC, 30); GH_FMA(wA, 31);
      *(float4*)&u.g.ghp[half][rg * 4] = acc0;
    } else if (tid < 576) {
      // gi via gather from W_c (stoch one-hot), 192 threads, pipelined gather
      const int rg = tid - 384;                // 0..191
      float4 acc = *(const float4*)&bc_s[rg * 4];
#pragma unroll
      for (int a = 0; a < AD; ++a)
        fma4(acc, Wc4[(size_t)(LD + a) * 192 + rg], act_all[t][a]);
      const bool skip = (t == 0) || first_all[t];
      if (!skip) {
        float4 gA[4], gB[4], gC[4];
        GI_LOAD(gA, 0); GI_LOAD(gB, 1);
#pragma unroll 1
        for (int gg = 0; gg < 2; ++gg) {
          const int g = gg * 3;
          GI_LOAD(gC, g + 2); GI_ADD(gA);
          GI_LOAD(gA, g + 3); GI_ADD(gB);
          GI_LOAD(gB, g + 4); GI_ADD(gC);
        }
        GI_ADD(gA); GI_ADD(gB);   // groups 6, 7
      }
      *(float4*)&u.g.gi[rg * 4] = acc;
    } else {
      // obs load (fallback path only)
      if (!use_op) {
        const int z = tid - 576;
        if (z < 64) {
          *(float4*)&obs_s[z * 4] =
              ntload4(&obs[((size_t)b0 * TT + t) * HD + z * 4]);
        }
      }
    }
    __syncthreads();

    // ================= P2: GRU gates =================
    if (tid < RD) {
      const int r = tid;
      const float ir = u.g.gi[r], iz = u.g.gi[r + 256], inn = u.g.gi[r + 512];
      const float hr = u.g.ghp[0][r      ] + u.g.ghp[1][r      ];
      const float hz = u.g.ghp[0][r + 256] + u.g.ghp[1][r + 256];
      const float hn = u.g.ghp[0][r + 512] + u.g.ghp[1][r + 512];
      const bool f = (first_all[t] != 0);
      const float dprev = f ? 0.f : deter_s[r];
      const float rr = 1.f / (1.f + __expf(-(ir + hr)));
      const float zz = 1.f / (1.f + __expf(-(iz + hz)));
      const float nn = tanhf(fmaf(rr, hn, inn));
      const float h = (1.f - zz) * nn + zz * dprev;
      deter_s[r] = h;
      __builtin_nontemporal_store(h, &out_deter[((size_t)b0 * TT + t) * RD + r]);
    }
    __syncthreads();

    // ================= P3: posterior deter-half, K-split x2, float2, pipelined =====
    {
      const int half = tid >> 9, o2 = tid & 511;
      const int cbase = half * 128;
      float2 acc0 = make_float2(0.f, 0.f);
      const float2* pp2w = &Wp2[(size_t)cbase * 512 + o2];
      float2 pA[4], pB[4], pC[4];
      PP_LOAD(pA, 0); PP_LOAD(pB, 1);
#pragma unroll 1
      for (int gg = 0; gg < 10; ++gg) {
        const int g = gg * 3;
        PP_LOAD(pC, g + 2); PP_FMA(pA, g);
        PP_LOAD(pA, g + 3); PP_FMA(pB, g + 1);
        PP_LOAD(pB, g + 4); PP_FMA(pC, g + 2);
      }
      PP_FMA(pA, 30); PP_FMA(pB, 31);
      if (!use_op) {
        // fold obs half: rows 256..511 of WpostT (fallback path, unpipelined)
#pragma unroll 4
        for (int c = 0; c < 128; c += 4) {
          const float2 w0 = Wp2[(size_t)(256 + cbase + c + 0) * 512 + o2];
          const float2 w1 = Wp2[(size_t)(256 + cbase + c + 1) * 512 + o2];
          const float2 w2 = Wp2[(size_t)(256 + cbase + c + 2) * 512 + o2];
          const float2 w3 = Wp2[(size_t)(256 + cbase + c + 3) * 512 + o2];
          const float4 o0 = *(const float4*)&obs_s[cbase + c];
          fma2(acc0, w0, o0.x); fma2(acc0, w1, o0.y); fma2(acc0, w2, o0.z); fma2(acc0, w3, o0.w);
        }
      }
      *(float2*)&u.pp[half][o2 * 2] = acc0;
    }
    __syncthreads();

    // ================= P4: logits + gumbel argmax + one-hot stoch =================
    {
      if (tid < 256) {
        const float4 p0 = *(const float4*)&u.pp[0][o4me * 4];
        const float4 p1 = *(const float4*)&u.pp[1][o4me * 4];
        float4 l;
        l.x = p0.x + p1.x + op4.x; l.y = p0.y + p1.y + op4.y;
        l.z = p0.z + p1.z + op4.z; l.w = p0.w + p1.w + op4.w;
        ntstore4(&out_logits[((size_t)b0 * TT + t) * LD + o4me * 4], l);
        float v[4] = {l.x + g4.x, l.y + g4.y, l.z + g4.z, l.w + g4.w};
        const int l0 = o4me * 4;
        float mv = v[0]; int mi = l0;
#pragma unroll
        for (int i = 1; i < 4; ++i)
          if (v[i] > mv) { mv = v[i]; mi = l0 + i; }
#pragma unroll
        for (int off = 1; off < 8; off <<= 1) {
          const float ov = __shfl_xor(mv, off);
          const int   oi = __shfl_xor(mi, off);
          if (ov > mv || (ov == mv && oi < mi)) { mv = ov; mi = oi; }
        }
        if ((o4me & 7) == 0) scol_s[o4me >> 3] = mi;   // mi in [g*32, g*32+32)
        float4 oh;
        oh.x = (mi == l0 + 0) ? 1.f : 0.f;
        oh.y = (mi == l0 + 1) ? 1.f : 0.f;
        oh.z = (mi == l0 + 2) ? 1.f : 0.f;
        oh.w = (mi == l0 + 3) ? 1.f : 0.f;
        ntstore4(&out_stoch[((size_t)b0 * TT + t) * LD + l0], oh);
      }
      // reset deter for t+1 episode starts (before P1(t+1) reads it)
      if (tid < 64) {
        if (t + 1 < TT && first_all[t + 1])
          *(float4*)&deter_s[tid * 4] = make_float4(0.f, 0.f, 0.f, 0.f);
      }
    }
    __syncthreads();
  }
}

extern "C" void kernel_launch(void* const* d_in, const int* in_sizes, int n_in,
                              void* d_out, int out_size, void* d_ws, size_t ws_size,
                              hipStream_t stream) {
  const float* obs    = (const float*)d_in[0];
  const float* action = (const float*)d_in[1];
  const int*   first  = (const int*)d_in[2];
  const float* gumbel = (const float*)d_in[3];
  const float* W_in   = (const float*)d_in[4];
  const float* b_in   = (const float*)d_in[5];
  const float* W_ih   = (const float*)d_in[6];
  const float* W_hh   = (const float*)d_in[7];
  const float* b_ih   = (const float*)d_in[8];
  const float* b_hh   = (const float*)d_in[9];
  const float* W_post = (const float*)d_in[10];
  const float* b_post = (const float*)d_in[11];

  float* ws      = (float*)d_ws;
  float* WihT    = ws + OFF_WIHT;
  float* WhhT    = ws + OFF_WHHT;
  float* WpostT  = ws + OFF_WPOSTT;
  float* WcT     = ws + OFF_WCT;
  float* bc      = ws + OFF_BC;
  float* obsproj = ws + OFF_OBSPROJ;
  const bool use_op = ws_size >= WS_FLOATS_FULL * sizeof(float);

  float* out_deter  = (float*)d_out;
  float* out_stoch  = out_deter + (size_t)BB * TT * RD;
  float* out_logits = out_stoch + (size_t)BB * TT * LD;

  transpose_k<<<dim3(256/32, 768/32), dim3(32, 8), 0, stream>>>(W_ih, WihT, 768, 256);
  transpose_k<<<dim3(256/32, 768/32), dim3(32, 8), 0, stream>>>(W_hh, WhhT, 768, 256);
  transpose_k<<<dim3(512/32, 1024/32), dim3(32, 8), 0, stream>>>(W_post, WpostT, 1024, 512);
  wc_kernel<<<1031, 256, 0, stream>>>(W_in, b_in, WihT, b_ih, WcT, bc);
  if (use_op)
    obsproj_gemm<<<dim3(1024/128, 32768/128), 256, 0, stream>>>(obs, W_post, b_post, obsproj);
  rssm_scan<<<BB, 1024, 0, stream>>>(obs, action, first, gumbel, WhhT, WpostT, WcT, bc,
                                     b_hh, b_post, use_op ? obsproj : (const float*)nullptr,
                                     out_deter, out_stoch, out_logits);
}